// Round 11
// baseline (484.131 us; speedup 1.0000x reference)
//
#include <hip/hip_runtime.h>
#include <hip/hip_bf16.h>

// Chamfer distance, B=16, N=M=4096, D=3, fp32 — LDS-free MFMA kernel.
//
// d2(s,t) = |s|^2+|t|^2-2 s.t via ONE K=16 bf16 mfma_f32_32x32x16 per 32x32
// tile with hi/lo bf16 splitting (slot layout verified absmax==0 R4..R10):
//   A: [xh yh zh xh yh zh xl yl | zl fh fl 1 1 0 0 0]           (query s)
//   B: [-2xh -2yh -2zh -2xl -2yl -2zl -2xh -2yh | -2zh 1 1 fh fl 0 0 0] (t)
// aug kernel prebuilds all B-records (2 roles x 65536 pts x 32 B = 4 MB,
// L2-resident) AND initializes mins=0xFF / out=0 (no hipMemset at all).
// Main kernel: NO LDS, NO barriers — B-fragments read straight from global
// (1 KB coalesced per wave-step, ~16x L2 reuse across strips), distance-2
// register prefetch, 4 MFMAs + 32 v_min3 per step. Grid: dir(2) x b(16) x
// strip(16 of 256 rows) x colhalf(2 of 2048) = 1024 blocks = 4 blocks/CU.
// Partial row-mins merge via uint-bits atomicMin; 64-block reduce finishes.

#define BATCH   16
#define NPTS    4096
#define NSTRIPS 16
#define COLSPB  2048
#define NSTEP   (COLSPB / 64)          // 32
#define NMINS   (2 * BATCH * NPTS)     // 131072

typedef __attribute__((ext_vector_type(8)))  short short8;
typedef __attribute__((ext_vector_type(16))) float float16;

union U4S8 { uint4 u; short8 s; };

__device__ inline unsigned int bfb(float v) {
    __hip_bfloat16 h = __float2bfloat16(v);
    unsigned short u; __builtin_memcpy(&u, &h, 2);
    return (unsigned int)u;
}
__device__ inline float bff(float v) { return __bfloat162float(__float2bfloat16(v)); }

#define ONEB 0x3F80u

__device__ inline void buildA(float x, float y, float z, uint4& w0, uint4& w1) {
    float xhf = bff(x), yhf = bff(y), zhf = bff(z);
    float f = fmaf(x, x, fmaf(y, y, z * z));
    float fhf = bff(f);
    unsigned xh = bfb(xhf), yh = bfb(yhf), zh = bfb(zhf);
    unsigned xl = bfb(x - xhf), yl = bfb(y - yhf), zl = bfb(z - zhf);
    unsigned fh = bfb(fhf), fl = bfb(f - fhf);
    w0 = make_uint4(xh | (yh << 16), zh | (xh << 16),
                    yh | (zh << 16), xl | (yl << 16));
    w1 = make_uint4(zl | (fh << 16), fl | (ONEB << 16), ONEB, 0u);
}

__device__ inline void buildB(float x, float y, float z, uint4& w0, uint4& w1) {
    float xhf = bff(x), yhf = bff(y), zhf = bff(z);
    float f = fmaf(x, x, fmaf(y, y, z * z));
    float fhf = bff(f);
    unsigned a = bfb(-2.0f * xhf), b = bfb(-2.0f * yhf), c = bfb(-2.0f * zhf);
    unsigned d = bfb(-2.0f * (x - xhf)), e = bfb(-2.0f * (y - yhf)),
             g = bfb(-2.0f * (z - zhf));
    unsigned fh = bfb(fhf), fl = bfb(f - fhf);
    w0 = make_uint4(a | (b << 16), c | (d << 16),
                    e | (g << 16), a | (b << 16));
    w1 = make_uint4(c | (ONEB << 16), ONEB | (fh << 16), fl, 0u);
}

// ---------- kernel 0: prebuild B-records + init mins/out ----------
__global__ __launch_bounds__(256) void aug_kernel(
    const float* __restrict__ src, const float* __restrict__ tgt,
    uint4* __restrict__ recs, unsigned int* __restrict__ mins,
    float* __restrict__ out)
{
    int i = blockIdx.x * 256 + threadIdx.x;   // 0 .. 131071 = role*65536 + p
    int role = i >> 16;                        // 0 = src, 1 = tgt
    int p = i & 0xFFFF;
    const float* base = role ? tgt : src;
    float x = base[3 * p + 0];
    float y = base[3 * p + 1];
    float z = base[3 * p + 2];
    uint4 w0, w1;
    buildB(x, y, z, w0, w1);
    recs[(size_t)i * 2 + 0] = w0;
    recs[(size_t)i * 2 + 1] = w1;
    mins[i] = 0xFFFFFFFFu;                     // +inf pattern for uint-min
    if (i == 0) out[0] = 0.0f;
}

// ---------- kernel 1: LDS-free MFMA + fold + atomicMin merge ----------
__global__ __launch_bounds__(256, 4) void chamfer_kernel(
    const float* __restrict__ src, const float* __restrict__ tgt,
    const uint4* __restrict__ recs, unsigned int* __restrict__ mins)
{
    int blk = blockIdx.x;
    const int chf   = blk & 1;              blk >>= 1;
    const int strip = blk & (NSTRIPS - 1);  blk >>= 4;
    const int b     = blk & 15;             blk >>= 4;
    const int dir   = blk;

    const int t    = threadIdx.x;
    const int lane = t & 63;
    const int w    = t >> 6;
    const int half = lane >> 5;
    const int l5   = lane & 31;

    const float* Araw = (dir ? tgt : src) + (size_t)b * NPTS * 3;   // queries
    // target role: dir0 -> tgt (role 1), dir1 -> src (role 0)
    const uint4* Bp = recs
        + ((size_t)((dir ? 0 : 1) * BATCH + b) * NPTS + chf * COLSPB) * 2;

    // A fragments: 2 row-groups of 32 rows per wave (256 rows per block).
    short8 afr[2];
#pragma unroll
    for (int g = 0; g < 2; g++) {
        int row = strip * 256 + g * 128 + w * 32 + l5;
        uint4 w0, w1;
        buildA(Araw[3 * row], Araw[3 * row + 1], Araw[3 * row + 2], w0, w1);
        U4S8 tt; tt.u = half ? w1 : w0;
        afr[g] = tt.s;
    }

    // Per step j: 64 cols = 2 fragments; lane reads uint4 at
    // (j*64 + f*32 + l5)*2 + half -> the wave covers 1 KB contiguous.
    auto fragAddr = [&](int j, int f) {
        return (size_t)(j * 64 + f * 32 + l5) * 2 + half;
    };

    float rm[2][16];
#pragma unroll
    for (int g = 0; g < 2; g++)
#pragma unroll
        for (int r = 0; r < 16; r++) rm[g][r] = 1e30f;

    const float16 z16 = {0.f,0.f,0.f,0.f,0.f,0.f,0.f,0.f,
                         0.f,0.f,0.f,0.f,0.f,0.f,0.f,0.f};

    // Distance-2 register prefetch pipeline; no barriers anywhere.
    U4S8 c0, c1, n0, n1, p0, p1;
    c0.u = Bp[fragAddr(0, 0)];
    c1.u = Bp[fragAddr(0, 1)];
    n0.u = Bp[fragAddr(1, 0)];
    n1.u = Bp[fragAddr(1, 1)];
#pragma unroll 4
    for (int j = 0; j < NSTEP; j++) {
        if (j + 2 < NSTEP) {
            p0.u = Bp[fragAddr(j + 2, 0)];
            p1.u = Bp[fragAddr(j + 2, 1)];
        }
        float16 a00 = __builtin_amdgcn_mfma_f32_32x32x16_bf16(afr[0], c0.s, z16, 0, 0, 0);
        float16 a01 = __builtin_amdgcn_mfma_f32_32x32x16_bf16(afr[0], c1.s, z16, 0, 0, 0);
        float16 a10 = __builtin_amdgcn_mfma_f32_32x32x16_bf16(afr[1], c0.s, z16, 0, 0, 0);
        float16 a11 = __builtin_amdgcn_mfma_f32_32x32x16_bf16(afr[1], c1.s, z16, 0, 0, 0);
#pragma unroll
        for (int r = 0; r < 16; r++) {
            rm[0][r] = fminf(fminf(a00[r], a01[r]), rm[0][r]);   // v_min3_f32
            rm[1][r] = fminf(fminf(a10[r], a11[r]), rm[1][r]);
        }
        c0 = n0; c1 = n1;
        n0 = p0; n1 = p1;
    }

    // Col-fold across l5 (cols 0..31 of each fragment, all steps merged).
#pragma unroll
    for (int mask = 1; mask <= 16; mask <<= 1)
#pragma unroll
        for (int g = 0; g < 2; g++)
#pragma unroll
            for (int r = 0; r < 16; r++)
                rm[g][r] = fminf(rm[g][r], __shfl_xor(rm[g][r], mask, 64));

    // Lanes l5==0 (one per half) hold partial mins for rows
    // strip*256 + g*128 + w*32 + (r&3) + 8*(r>>2) + 4*half (R7-proven map).
    if (l5 == 0) {
        unsigned int* mrow = mins + (size_t)(dir * BATCH + b) * NPTS;
#pragma unroll
        for (int g = 0; g < 2; g++)
#pragma unroll
            for (int r = 0; r < 16; r++) {
                int row = strip * 256 + g * 128 + w * 32
                        + (r & 3) + 8 * (r >> 2) + 4 * half;
                float v = fmaxf(rm[g][r], 0.0f);
                atomicMin(&mrow[row], __float_as_uint(v));
            }
    }
}

// ---------- kernel 2: final sum ----------
__global__ __launch_bounds__(256) void chamfer_reduce_kernel(
    const unsigned int* __restrict__ mins, float* __restrict__ out)
{
    const uint4* m4 = (const uint4*)mins;
    float s = 0.0f;
#pragma unroll
    for (int k = 0; k < 2; k++) {
        uint4 v = m4[(size_t)(blockIdx.x * 512 + k * 256 + threadIdx.x)];
        s += __uint_as_float(v.x) + __uint_as_float(v.y)
           + __uint_as_float(v.z) + __uint_as_float(v.w);
    }
#pragma unroll
    for (int off = 32; off > 0; off >>= 1) s += __shfl_down(s, off, 64);
    __shared__ float wsum[4];
    int lane = threadIdx.x & 63;
    int w = threadIdx.x >> 6;
    if (lane == 0) wsum[w] = s;
    __syncthreads();
    if (threadIdx.x == 0) {
        float tot = wsum[0] + wsum[1] + wsum[2] + wsum[3];
        atomicAdd(out, tot * (1.0f / (float)NPTS));
    }
}

extern "C" void kernel_launch(void* const* d_in, const int* in_sizes, int n_in,
                              void* d_out, int out_size, void* d_ws, size_t ws_size,
                              hipStream_t stream)
{
    const float* src = (const float*)d_in[0];
    const float* tgt = (const float*)d_in[1];
    float* out = (float*)d_out;

    uint4*        recs = (uint4*)d_ws;                       // 131072 x 32 B
    unsigned int* mins = (unsigned int*)(recs + (size_t)NMINS * 2);  // 131072 u32

    aug_kernel<<<NMINS / 256, 256, 0, stream>>>(src, tgt, recs, mins, out);
    chamfer_kernel<<<2 * BATCH * NSTRIPS * 2, 256, 0, stream>>>(src, tgt, recs, mins);
    chamfer_reduce_kernel<<<64, 256, 0, stream>>>(mins, out);   // 64*512 u4 = 131072
}

// Round 12
// 95.708 us; speedup vs baseline: 5.0584x; 5.0584x over previous
//
#include <hip/hip_runtime.h>
#include <hip/hip_bf16.h>

// Chamfer distance, B=16, N=M=4096, D=3, fp32 — LDS-free MFMA kernel, take 2.
//
// R11 failed on REGISTER SPILL (launch_bounds(256,4) = 128-VGPR cap vs ~110
// live -> 1.3 GB scratch writes). Fix: (256,2) = 256-VGPR budget + tighter
// fold (per row-group, 32 live MFMA-result floats max). Everything else as
// R11: d2 via ONE K=16 bf16 mfma_f32_32x32x16 per 32x32 tile, hi/lo split
// (slot layout verified absmax==0 R4..R11):
//   A: [xh yh zh xh yh zh xl yl | zl fh fl 1 1 0 0 0]           (query s)
//   B: [-2xh -2yh -2zh -2xl -2yl -2zl -2xh -2yh | -2zh 1 1 fh fl 0 0 0] (t)
// aug kernel prebuilds B-records (4 MB, L2-resident) + inits mins/out.
// Main kernel: no LDS, no barriers; B-fragments read from global (coalesced
// 2 KB per wave-step, L2-cached), distance-2 register prefetch, 4 MFMAs +
// 2x32 v_min3 per step. Grid 1024 = dir(2) x b(16) x strip(16) x colhalf(2).
// Partial row-mins -> uint-bits atomicMin; 64-block reduce finishes.

#define BATCH   16
#define NPTS    4096
#define NSTRIPS 16
#define COLSPB  2048
#define NSTEP   (COLSPB / 64)          // 32
#define NMINS   (2 * BATCH * NPTS)     // 131072

typedef __attribute__((ext_vector_type(8)))  short short8;
typedef __attribute__((ext_vector_type(16))) float float16;

union U4S8 { uint4 u; short8 s; };

__device__ inline unsigned int bfb(float v) {
    __hip_bfloat16 h = __float2bfloat16(v);
    unsigned short u; __builtin_memcpy(&u, &h, 2);
    return (unsigned int)u;
}
__device__ inline float bff(float v) { return __bfloat162float(__float2bfloat16(v)); }

#define ONEB 0x3F80u

__device__ inline void buildA(float x, float y, float z, uint4& w0, uint4& w1) {
    float xhf = bff(x), yhf = bff(y), zhf = bff(z);
    float f = fmaf(x, x, fmaf(y, y, z * z));
    float fhf = bff(f);
    unsigned xh = bfb(xhf), yh = bfb(yhf), zh = bfb(zhf);
    unsigned xl = bfb(x - xhf), yl = bfb(y - yhf), zl = bfb(z - zhf);
    unsigned fh = bfb(fhf), fl = bfb(f - fhf);
    w0 = make_uint4(xh | (yh << 16), zh | (xh << 16),
                    yh | (zh << 16), xl | (yl << 16));
    w1 = make_uint4(zl | (fh << 16), fl | (ONEB << 16), ONEB, 0u);
}

__device__ inline void buildB(float x, float y, float z, uint4& w0, uint4& w1) {
    float xhf = bff(x), yhf = bff(y), zhf = bff(z);
    float f = fmaf(x, x, fmaf(y, y, z * z));
    float fhf = bff(f);
    unsigned a = bfb(-2.0f * xhf), b = bfb(-2.0f * yhf), c = bfb(-2.0f * zhf);
    unsigned d = bfb(-2.0f * (x - xhf)), e = bfb(-2.0f * (y - yhf)),
             g = bfb(-2.0f * (z - zhf));
    unsigned fh = bfb(fhf), fl = bfb(f - fhf);
    w0 = make_uint4(a | (b << 16), c | (d << 16),
                    e | (g << 16), a | (b << 16));
    w1 = make_uint4(c | (ONEB << 16), ONEB | (fh << 16), fl, 0u);
}

// ---------- kernel 0: prebuild B-records + init mins/out ----------
__global__ __launch_bounds__(256) void aug_kernel(
    const float* __restrict__ src, const float* __restrict__ tgt,
    uint4* __restrict__ recs, unsigned int* __restrict__ mins,
    float* __restrict__ out)
{
    int i = blockIdx.x * 256 + threadIdx.x;   // 0 .. 131071 = role*65536 + p
    int role = i >> 16;                        // 0 = src, 1 = tgt
    int p = i & 0xFFFF;
    const float* base = role ? tgt : src;
    float x = base[3 * p + 0];
    float y = base[3 * p + 1];
    float z = base[3 * p + 2];
    uint4 w0, w1;
    buildB(x, y, z, w0, w1);
    recs[(size_t)i * 2 + 0] = w0;
    recs[(size_t)i * 2 + 1] = w1;
    mins[i] = 0xFFFFFFFFu;                     // +inf pattern for uint-min
    if (i == 0) out[0] = 0.0f;
}

// ---------- kernel 1: LDS-free MFMA + fold + atomicMin merge ----------
__global__ __launch_bounds__(256, 2) void chamfer_kernel(
    const float* __restrict__ src, const float* __restrict__ tgt,
    const uint4* __restrict__ recs, unsigned int* __restrict__ mins)
{
    int blk = blockIdx.x;
    const int chf   = blk & 1;              blk >>= 1;
    const int strip = blk & (NSTRIPS - 1);  blk >>= 4;
    const int b     = blk & 15;             blk >>= 4;
    const int dir   = blk;

    const int t    = threadIdx.x;
    const int lane = t & 63;
    const int w    = t >> 6;
    const int half = lane >> 5;
    const int l5   = lane & 31;

    const float* Araw = (dir ? tgt : src) + (size_t)b * NPTS * 3;   // queries
    // target role: dir0 -> tgt (role 1), dir1 -> src (role 0)
    const uint4* Bp = recs
        + ((size_t)((dir ? 0 : 1) * BATCH + b) * NPTS + chf * COLSPB) * 2;

    // A fragments: 2 row-groups of 32 rows per wave (256 rows per block).
    short8 afr[2];
#pragma unroll
    for (int g = 0; g < 2; g++) {
        int row = strip * 256 + g * 128 + w * 32 + l5;
        uint4 w0, w1;
        buildA(Araw[3 * row], Araw[3 * row + 1], Araw[3 * row + 2], w0, w1);
        U4S8 tt; tt.u = half ? w1 : w0;
        afr[g] = tt.s;
    }

    // Per step j: 64 cols = 2 fragments; lane reads uint4 at
    // (j*64 + f*32 + l5)*2 + half -> the wave covers 2 KB contiguous.
    auto fragAddr = [&](int j, int f) {
        return (size_t)(j * 64 + f * 32 + l5) * 2 + half;
    };

    float rm[2][16];
#pragma unroll
    for (int g = 0; g < 2; g++)
#pragma unroll
        for (int r = 0; r < 16; r++) rm[g][r] = 1e30f;

    const float16 z16 = {0.f,0.f,0.f,0.f,0.f,0.f,0.f,0.f,
                         0.f,0.f,0.f,0.f,0.f,0.f,0.f,0.f};

    // Distance-2 register prefetch pipeline; no barriers anywhere.
    U4S8 c0, c1, n0, n1, p0, p1;
    c0.u = Bp[fragAddr(0, 0)];
    c1.u = Bp[fragAddr(0, 1)];
    n0.u = Bp[fragAddr(1, 0)];
    n1.u = Bp[fragAddr(1, 1)];
#pragma unroll 4
    for (int j = 0; j < NSTEP; j++) {
        if (j + 2 < NSTEP) {
            p0.u = Bp[fragAddr(j + 2, 0)];
            p1.u = Bp[fragAddr(j + 2, 1)];
        }
        // Per row-group: 2 MFMAs then immediate 16x min3 fold — caps live
        // MFMA-result floats at 32 (was 64 in R11's spilling version).
#pragma unroll
        for (int g = 0; g < 2; g++) {
            float16 a0 = __builtin_amdgcn_mfma_f32_32x32x16_bf16(afr[g], c0.s, z16, 0, 0, 0);
            float16 a1 = __builtin_amdgcn_mfma_f32_32x32x16_bf16(afr[g], c1.s, z16, 0, 0, 0);
#pragma unroll
            for (int r = 0; r < 16; r++)
                rm[g][r] = fminf(fminf(a0[r], a1[r]), rm[g][r]);   // v_min3_f32
        }
        c0 = n0; c1 = n1;
        n0 = p0; n1 = p1;
    }

    // Col-fold across l5 (cols 0..31 of each fragment, all steps merged).
#pragma unroll
    for (int mask = 1; mask <= 16; mask <<= 1)
#pragma unroll
        for (int g = 0; g < 2; g++)
#pragma unroll
            for (int r = 0; r < 16; r++)
                rm[g][r] = fminf(rm[g][r], __shfl_xor(rm[g][r], mask, 64));

    // Lanes l5==0 (one per half) hold partial mins for rows
    // strip*256 + g*128 + w*32 + (r&3) + 8*(r>>2) + 4*half (R7-proven map).
    if (l5 == 0) {
        unsigned int* mrow = mins + (size_t)(dir * BATCH + b) * NPTS;
#pragma unroll
        for (int g = 0; g < 2; g++)
#pragma unroll
            for (int r = 0; r < 16; r++) {
                int row = strip * 256 + g * 128 + w * 32
                        + (r & 3) + 8 * (r >> 2) + 4 * half;
                float v = fmaxf(rm[g][r], 0.0f);
                atomicMin(&mrow[row], __float_as_uint(v));
            }
    }
}

// ---------- kernel 2: final sum ----------
__global__ __launch_bounds__(256) void chamfer_reduce_kernel(
    const unsigned int* __restrict__ mins, float* __restrict__ out)
{
    const uint4* m4 = (const uint4*)mins;
    float s = 0.0f;
#pragma unroll
    for (int k = 0; k < 2; k++) {
        uint4 v = m4[(size_t)(blockIdx.x * 512 + k * 256 + threadIdx.x)];
        s += __uint_as_float(v.x) + __uint_as_float(v.y)
           + __uint_as_float(v.z) + __uint_as_float(v.w);
    }
#pragma unroll
    for (int off = 32; off > 0; off >>= 1) s += __shfl_down(s, off, 64);
    __shared__ float wsum[4];
    int lane = threadIdx.x & 63;
    int w = threadIdx.x >> 6;
    if (lane == 0) wsum[w] = s;
    __syncthreads();
    if (threadIdx.x == 0) {
        float tot = wsum[0] + wsum[1] + wsum[2] + wsum[3];
        atomicAdd(out, tot * (1.0f / (float)NPTS));
    }
}

extern "C" void kernel_launch(void* const* d_in, const int* in_sizes, int n_in,
                              void* d_out, int out_size, void* d_ws, size_t ws_size,
                              hipStream_t stream)
{
    const float* src = (const float*)d_in[0];
    const float* tgt = (const float*)d_in[1];
    float* out = (float*)d_out;

    uint4*        recs = (uint4*)d_ws;                       // 131072 x 32 B
    unsigned int* mins = (unsigned int*)(recs + (size_t)NMINS * 2);  // 131072 u32

    aug_kernel<<<NMINS / 256, 256, 0, stream>>>(src, tgt, recs, mins, out);
    chamfer_kernel<<<2 * BATCH * NSTRIPS * 2, 256, 0, stream>>>(src, tgt, recs, mins);
    chamfer_reduce_kernel<<<64, 256, 0, stream>>>(mins, out);   // 64*512 u4 = 131072
}

// Round 13
// 88.459 us; speedup vs baseline: 5.4729x; 1.0819x over previous
//
#include <hip/hip_runtime.h>
#include <hip/hip_bf16.h>

// Chamfer distance, B=16, N=M=4096, D=3, fp32 — R10 skeleton + prebuilt recs.
//
// d2 via ONE K=16 bf16 mfma_f32_32x32x16 per 32x32 tile, hi/lo bf16 split
// (slot layout verified absmax==0 in R4..R12):
//   A: [xh yh zh xh yh zh xl yl | zl fh fl 1 1 0 0 0]           (query s)
//   B: [-2xh -2yh -2zh -2xl -2yl -2zl -2xh -2yh | -2zh 1 1 fh fl 0 0 0] (t)
// aug kernel prebuilds B-records once (lo/hi arrays, 4 MB total) — removes
// R10's 16x-redundant in-kernel conversion (~9 us chip VALU). Main kernel:
// grid dir(2) x b(16) x strip(16 of 256 rows) = 512 x 256 thr; g=2 row-
// groups/wave (each B-fragment feeds 2 MFMAs); CHUNKC=1024 double-buffered
// LDS (64 KB, 2 blocks/CU) staged via async global_load_lds width=16
// (R5-proven pattern); register-prefetch inner loop (R10-proven); row-mins
// FINAL per block -> one atomicAdd. 2 dispatches; out zeroed by aug.

#define BATCH   16
#define NPTS    4096
#define CHUNKC  1024
#define NCHUNKS (NPTS / CHUNKC)        // 4
#define NSTRIPS 16                     // 4096 / 256 rows per block
#define NSTEP   (CHUNKC / 64)          // 16
#define NPER    (BATCH * NPTS)         // 65536 points per role

typedef __attribute__((ext_vector_type(8)))  short short8;
typedef __attribute__((ext_vector_type(16))) float float16;

union U4S8 { uint4 u; short8 s; };

__device__ inline unsigned int bfb(float v) {
    __hip_bfloat16 h = __float2bfloat16(v);
    unsigned short u; __builtin_memcpy(&u, &h, 2);
    return (unsigned int)u;
}
__device__ inline float bff(float v) { return __bfloat162float(__float2bfloat16(v)); }

#define ONEB 0x3F80u

__device__ inline void buildA(float x, float y, float z, uint4& w0, uint4& w1) {
    float xhf = bff(x), yhf = bff(y), zhf = bff(z);
    float f = fmaf(x, x, fmaf(y, y, z * z));
    float fhf = bff(f);
    unsigned xh = bfb(xhf), yh = bfb(yhf), zh = bfb(zhf);
    unsigned xl = bfb(x - xhf), yl = bfb(y - yhf), zl = bfb(z - zhf);
    unsigned fh = bfb(fhf), fl = bfb(f - fhf);
    w0 = make_uint4(xh | (yh << 16), zh | (xh << 16),
                    yh | (zh << 16), xl | (yl << 16));
    w1 = make_uint4(zl | (fh << 16), fl | (ONEB << 16), ONEB, 0u);
}

__device__ inline void buildB(float x, float y, float z, uint4& w0, uint4& w1) {
    float xhf = bff(x), yhf = bff(y), zhf = bff(z);
    float f = fmaf(x, x, fmaf(y, y, z * z));
    float fhf = bff(f);
    unsigned a = bfb(-2.0f * xhf), b = bfb(-2.0f * yhf), c = bfb(-2.0f * zhf);
    unsigned d = bfb(-2.0f * (x - xhf)), e = bfb(-2.0f * (y - yhf)),
             g = bfb(-2.0f * (z - zhf));
    unsigned fh = bfb(fhf), fl = bfb(f - fhf);
    w0 = make_uint4(a | (b << 16), c | (d << 16),
                    e | (g << 16), a | (b << 16));
    w1 = make_uint4(c | (ONEB << 16), ONEB | (fh << 16), fl, 0u);
}

// ---------- kernel 0: prebuild B-records (lo/hi split) + zero out ----------
__global__ __launch_bounds__(256) void aug_kernel(
    const float* __restrict__ src, const float* __restrict__ tgt,
    uint4* __restrict__ Blo, uint4* __restrict__ Bhi, float* __restrict__ out)
{
    int i = blockIdx.x * 256 + threadIdx.x;   // role*NPER + p
    int role = i >> 16;                        // 0 = src, 1 = tgt
    int p = i & (NPER - 1);
    const float* base = role ? tgt : src;
    float x = base[3 * p + 0];
    float y = base[3 * p + 1];
    float z = base[3 * p + 2];
    uint4 w0, w1;
    buildB(x, y, z, w0, w1);
    Blo[i] = w0;
    Bhi[i] = w1;
    if (i == 0) out[0] = 0.0f;
}

// ---------- kernel 1: MFMA main (R10 loop, async-staged records) ----------
__global__ __launch_bounds__(256, 2) void chamfer_kernel(
    const float* __restrict__ src, const float* __restrict__ tgt,
    const uint4* __restrict__ Blo, const uint4* __restrict__ Bhi,
    float* __restrict__ out)
{
    __shared__ uint4 sbuf[2][2][CHUNKC];    // [buf][half][pt] = 64 KB
    __shared__ float wsum[4];

    int blk = blockIdx.x;
    const int strip = blk & (NSTRIPS - 1); blk >>= 4;
    const int b     = blk & 15;            blk >>= 4;
    const int dir   = blk;

    const int t    = threadIdx.x;
    const int lane = t & 63;
    const int w    = t >> 6;
    const int half = lane >> 5;
    const int l5   = lane & 31;

    const float* Araw = (dir ? tgt : src) + (size_t)b * NPTS * 3;   // queries
    // target role: dir0 -> tgt (role 1), dir1 -> src (role 0)
    const size_t Boff = (size_t)((dir ? 0 : 1) * BATCH + b) * NPTS;

    // A fragments: 2 row-groups of 32 rows per wave (256 rows per block).
    short8 afr[2];
#pragma unroll
    for (int g = 0; g < 2; g++) {
        int row = strip * 256 + g * 128 + w * 32 + l5;
        uint4 w0, w1;
        buildA(Araw[3 * row], Araw[3 * row + 1], Araw[3 * row + 2], w0, w1);
        U4S8 tt; tt.u = half ? w1 : w0;
        afr[g] = tt.s;
    }

    // Async staging: chunk c (1024 pts x 32 B) -> buffer bi. Per half: 4
    // wave-uniform segments of 64 x 16 B (R5-proven global_load_lds pattern).
    auto stage = [&](int c, int bi) {
#pragma unroll
        for (int h = 0; h < 2; h++) {
            const uint4* gbase = (h ? Bhi : Blo) + Boff + c * CHUNKC;
#pragma unroll
            for (int j = 0; j < 4; j++) {
                int li = w * 256 + j * 64;               // wave-uniform
                __builtin_amdgcn_global_load_lds(
                    (const __attribute__((address_space(1))) unsigned int*)(gbase + li + lane),
                    (__attribute__((address_space(3))) unsigned int*)&sbuf[bi][h][li],
                    16, 0, 0);
            }
        }
    };

    const float16 z16 = {0.f,0.f,0.f,0.f,0.f,0.f,0.f,0.f,
                         0.f,0.f,0.f,0.f,0.f,0.f,0.f,0.f};
    float rm[2][16];
#pragma unroll
    for (int g = 0; g < 2; g++)
#pragma unroll
        for (int r = 0; r < 16; r++) rm[g][r] = 1e30f;

    stage(0, 0);
    for (int c = 0; c < NCHUNKS; c++) {
        __syncthreads();              // stage(c) drained; buf[(c+1)&1] free
        if (c + 1 < NCHUNKS) stage(c + 1, (c + 1) & 1);   // async, no wait
        const int bi = c & 1;

        // R10-proven software-pipelined MFMA loop.
        U4S8 c0, c1, n0, n1;
        c0.u = sbuf[bi][half][l5];
        c1.u = sbuf[bi][half][32 + l5];
#pragma unroll 4
        for (int j2 = 0; j2 < NSTEP; j2++) {
            int nj = (j2 + 1) & (NSTEP - 1);             // wrap: harmless re-read
            n0.u = sbuf[bi][half][nj * 64 + l5];
            n1.u = sbuf[bi][half][nj * 64 + 32 + l5];
#pragma unroll
            for (int g = 0; g < 2; g++) {
                float16 a0 = __builtin_amdgcn_mfma_f32_32x32x16_bf16(afr[g], c0.s, z16, 0, 0, 0);
                float16 a1 = __builtin_amdgcn_mfma_f32_32x32x16_bf16(afr[g], c1.s, z16, 0, 0, 0);
#pragma unroll
                for (int r = 0; r < 16; r++)
                    rm[g][r] = fminf(fminf(a0[r], a1[r]), rm[g][r]);   // v_min3
            }
            c0 = n0; c1 = n1;
        }
    }

    // Col-fold within half (masks 1..16 over lane&31); each lane then holds
    // 2x16 final rows for its half; shfl 32 merges the halves' sums.
#pragma unroll
    for (int mask = 1; mask <= 16; mask <<= 1)
#pragma unroll
        for (int g = 0; g < 2; g++)
#pragma unroll
            for (int r = 0; r < 16; r++)
                rm[g][r] = fminf(rm[g][r], __shfl_xor(rm[g][r], mask, 64));

    float s = 0.0f;
#pragma unroll
    for (int g = 0; g < 2; g++)
#pragma unroll
        for (int r = 0; r < 16; r++) s += fmaxf(rm[g][r], 0.0f);
    s += __shfl_xor(s, 32, 64);

    if (lane == 0) wsum[w] = s;
    __syncthreads();
    if (t == 0)
        atomicAdd(out, (wsum[0] + wsum[1] + wsum[2] + wsum[3]) * (1.0f / (float)NPTS));
}

extern "C" void kernel_launch(void* const* d_in, const int* in_sizes, int n_in,
                              void* d_out, int out_size, void* d_ws, size_t ws_size,
                              hipStream_t stream)
{
    const float* src = (const float*)d_in[0];
    const float* tgt = (const float*)d_in[1];
    float* out = (float*)d_out;

    uint4* Blo = (uint4*)d_ws;                 // 2*NPER x 16 B
    uint4* Bhi = Blo + 2 * NPER;               // 2*NPER x 16 B

    aug_kernel<<<2 * NPER / 256, 256, 0, stream>>>(src, tgt, Blo, Bhi, out);
    chamfer_kernel<<<2 * BATCH * NSTRIPS, 256, 0, stream>>>(src, tgt, Blo, Bhi, out);
}